// Round 1
// baseline (165.945 us; speedup 1.0000x reference)
//
#include <hip/hip_runtime.h>
#include <math.h>

#define N_TRIAL 1000000
#define N_REF 8
#define N_DIM 16
#define BETA 1.0f
#define GAMMA 0.001f
// N_SELECT = {1,2,3,1} packed as nibbles
#define N_SELECT_PACKED 0x1321

#define WPB 4          // waves per block
#define D2_STRIDE 72   // 64+8: writes (16s+q)%32 and reads (8r+lane)%32 both 2-way = free

typedef float v4f  __attribute__((ext_vector_type(4)));
typedef int   v4iu __attribute__((ext_vector_type(4), aligned(4)));  // dword-aligned int4

// Full 4-lane-quad sum via two DPP quad_perm butterfly adds.
// Runs on the VALU pipe (~4cy each, no lgkmcnt wait) instead of the two
// ds_swizzle round-trips (~100cy + shared-LDS-pipe occupancy) the old
// __shfl_xor(d2,1)/(d2,2) pair compiled to. Replicates the full 16-dim
// sum into all 4 lanes of the quad, same as the shfl butterfly.
//   0xB1 = quad_perm[1,0,3,2] (lane ^ 1),  0x4E = quad_perm[2,3,0,1] (lane ^ 2)
__device__ __forceinline__ float quad_sum(float x) {
    int   x0 = __builtin_bit_cast(int, x);
    float a  = __builtin_bit_cast(float,
               __builtin_amdgcn_update_dpp(0, x0, 0xB1, 0xF, 0xF, true));
    float y  = x + a;
    int   y0 = __builtin_bit_cast(int, y);
    float b  = __builtin_bit_cast(float,
               __builtin_amdgcn_update_dpp(0, y0, 0x4E, 0xF, 0xF, true));
    return y + b;
}

// Per-wave, barrier-free two-phase kernel.
//   staging : wave's 64 stim rows (2304 B) copied dense+coalesced into LDS
//   phase 1 : quad-per-trial gathers (9 lines/trial = floor) + weighted dist;
//             quad reduction now on the VALU pipe (DPP), group/attw rows
//             preloaded so the per-pass critical path is gather->dot->DPP->store
//   phase 2 : thread-per-trial tail (no 4x replication of sqrt/exp/suffix)
// All LDS dependencies are intra-wave -> no __syncthreads. LDS-pipe ops per
// wave cut ~123 -> ~55 (removed 64 ds_swizzle + 4 ds_bpermute).
// __launch_bounds__(256,8): pin 8 waves/EU so the wq[] preload (+16 VGPR)
// cannot push the allocator over the 64-VGPR occupancy cliff.
__global__ __launch_bounds__(256, 8) void likelihood_kernel(
    const int* __restrict__ stim,     // N_TRIAL x 9
    const int* __restrict__ config,   // N_TRIAL
    const int* __restrict__ group,    // N_TRIAL
    const int* __restrict__ present,  // N_TRIAL x 9
    const float* __restrict__ embed,  // N_STIM x 16
    const float* __restrict__ attw,   // N_GROUP x 16
    float* __restrict__ out)          // N_TRIAL
{
    __shared__ int4  s_stim4[WPB][144];            // 64 trials x 9 ints, dense
    __shared__ float s_d2[WPB][N_REF][D2_STRIDE];  // [ref][trial] transpose

    const int tid  = threadIdx.x;
    const int wv   = tid >> 6;
    const int lane = tid & 63;
    const int q    = lane >> 2;   // quad id 0..15
    const int s    = lane & 3;    // float4 segment 0..3

    int wtb = blockIdx.x * 256 + wv * 64;          // this wave's 64 trials
    const bool valid = (wtb + lane) < N_TRIAL;
    if (wtb > N_TRIAL - 64) wtb = N_TRIAL - 64;    // N_TRIAL % 64 == 0

    // ---- dense coalesced staging of stim (16B-aligned: 64*9*4 = 2304) ----
    {
        const int4* g4 = (const int4*)(stim + wtb * 9);   // 144 int4 per wave
        s_stim4[wv][lane]      = g4[lane];
        s_stim4[wv][64 + lane] = g4[64 + lane];
        if (lane < 16) s_stim4[wv][128 + lane] = g4[128 + lane];
    }

    // ---- group id + attention row for each of this lane's 4 quad-trials,
    //      loaded directly and hoisted off the per-pass critical path.
    //      (replaces the old gall load + 4x ds_bpermute __shfl)
    //      group load: 16 distinct consecutive ints, 4-way quad broadcast
    //      = one 64B line per instr. attw: 256B table, L1-hot.
    v4f wq[4];
#pragma unroll
    for (int j = 0; j < 4; ++j) {
        int g = group[wtb + 16 * j + q];
        wq[j] = *(const v4f*)(attw + g * N_DIM + s * 4);
    }

    // ---- coalesced stream loads, issued early to fly under phase 1 ----
    const int t2 = wtb + lane;                     // phase-2 trial (always valid addr)
    const int* pp = present + t2 * 9;
    v4iu p0 = *(const v4iu*)(pp + 1);              // present[1..4]
    v4iu p1 = *(const v4iu*)(pp + 5);              // present[5..8]
    int  c  = config[t2];

    const float* embed_s = embed + s * 4;          // this lane's row segment

    // ---------------- Phase 1: quad layout, 4 passes x 16 trials ----------
#pragma unroll
    for (int j = 0; j < 4; ++j) {
        const int* sp = (const int*)&s_stim4[wv][0] + (16 * j + q) * 9;
        int idx[9];
#pragma unroll
        for (int i = 0; i < 9; ++i) idx[i] = sp[i];   // conflict-free banks

        const v4f w  = wq[j];
        v4f zq = *(const v4f*)(embed_s + idx[0] * N_DIM);

        float d2v[N_REF];
#pragma unroll
        for (int r = 0; r < N_REF; ++r) {
            v4f zr = *(const v4f*)(embed_s + idx[1 + r] * N_DIM);
            v4f dd = zq - zr;
            v4f wd = w * dd;
            float d2 = (wd.x * dd.x + wd.y * dd.y) + (wd.z * dd.z + wd.w * dd.w);
            d2v[r] = quad_sum(d2);    // DPP butterfly: full 16-dim sum, VALU pipe
        }
        // lane s persists rows 2s, 2s+1 (uses the quad replication)
        float da = (s == 0) ? d2v[0] : (s == 1) ? d2v[2] : (s == 2) ? d2v[4] : d2v[6];
        float db = (s == 0) ? d2v[1] : (s == 1) ? d2v[3] : (s == 2) ? d2v[5] : d2v[7];
        s_d2[wv][2 * s    ][16 * j + q] = da;
        s_d2[wv][2 * s + 1][16 * j + q] = db;
    }
    // intra-wave ds_write -> ds_read ordering handled by compiler lgkmcnt;
    // no __syncthreads (all LDS state is per-wave).

    // ---------------- Phase 2: thread-per-trial tail -----------------------
    int pr[N_REF] = {p0.x, p0.y, p0.z, p0.w, p1.x, p1.y, p1.z, p1.w};

    float sim[N_REF];
#pragma unroll
    for (int r = 0; r < N_REF; ++r) {
        float d2 = s_d2[wv][r][lane];
        sim[r] = (__expf(-BETA * sqrtf(d2)) + GAMMA) * (float)pr[r];
    }

    int ns = (N_SELECT_PACKED >> ((c & 3) * 4)) & 0xF;   // ns in {1,2,3}

    // only suffix[0..2] can be selected (max N_SELECT == 3)
    float suf2 = sim[7];
#pragma unroll
    for (int r = 6; r >= 2; --r) suf2 += sim[r];
    float suf1 = suf2 + sim[1];
    float suf0 = suf1 + sim[0];

    float num = sim[0] * ((ns >= 2) ? sim[1] : 1.0f) * ((ns >= 3) ? sim[2] : 1.0f);
    float den = suf0   * ((ns >= 2) ? suf1   : 1.0f) * ((ns >= 3) ? suf2   : 1.0f);

    if (valid)
        out[wtb + lane] = __fdividef(num, den);   // fully coalesced store
}

extern "C" void kernel_launch(void* const* d_in, const int* in_sizes, int n_in,
                              void* d_out, int out_size, void* d_ws, size_t ws_size,
                              hipStream_t stream) {
    const int*   stim    = (const int*)d_in[0];
    const int*   config  = (const int*)d_in[1];
    const int*   group   = (const int*)d_in[2];
    const int*   present = (const int*)d_in[3];
    const float* embed   = (const float*)d_in[4];
    const float* attw    = (const float*)d_in[5];
    float*       out     = (float*)d_out;

    int blocks = (N_TRIAL + 255) / 256;   // 3907; tail handled by clamp+valid
    likelihood_kernel<<<blocks, 256, 0, stream>>>(stim, config, group, present,
                                                  embed, attw, out);
}

// Round 2
// 140.827 us; speedup vs baseline: 1.1784x; 1.1784x over previous
//
#include <hip/hip_runtime.h>
#include <math.h>

#define N_TRIAL 1000000
#define N_REF 8
#define N_DIM 16
#define BETA 1.0f
#define GAMMA 0.001f
// N_SELECT = {1,2,3,1} packed as nibbles
#define N_SELECT_PACKED 0x1321

#define WPB 4          // waves per block
#define D2_STRIDE 72   // 64+8: writes (16s+q)%32 and reads (8r+lane)%32 both 2-way = free

typedef float v4f  __attribute__((ext_vector_type(4)));
typedef int   v4iu __attribute__((ext_vector_type(4), aligned(4)));  // dword-aligned int4

// Full 4-lane-quad sum via two DPP quad_perm butterfly adds.
// VALU pipe (~4cy each, no lgkmcnt wait) instead of the two ds_swizzle
// round-trips the old __shfl_xor(d2,1)/(d2,2) pair compiled to.
//   0xB1 = quad_perm[1,0,3,2] (lane ^ 1),  0x4E = quad_perm[2,3,0,1] (lane ^ 2)
__device__ __forceinline__ float quad_sum(float x) {
    int   x0 = __builtin_bit_cast(int, x);
    float a  = __builtin_bit_cast(float,
               __builtin_amdgcn_update_dpp(0, x0, 0xB1, 0xF, 0xF, true));
    float y  = x + a;
    int   y0 = __builtin_bit_cast(int, y);
    float b  = __builtin_bit_cast(float,
               __builtin_amdgcn_update_dpp(0, y0, 0x4E, 0xF, 0xF, true));
    return y + b;
}

// Per-wave, barrier-free two-phase kernel.
// Round-2 fix: round 1 spilled (WRITE_SIZE 3.9->39 MB) because wq[4] (16 VGPR
// live across phase 1) + the __launch_bounds__(256,8) 64-VGPR pin forced
// scratch. Now: preload only the 4 group ids (4 VGPR); load the L1-hot attw
// row per pass; no min-wave pin. DPP quad reduction retained (the actual
// experiment round 1 failed to run).
__global__ __launch_bounds__(256) void likelihood_kernel(
    const int* __restrict__ stim,     // N_TRIAL x 9
    const int* __restrict__ config,   // N_TRIAL
    const int* __restrict__ group,    // N_TRIAL
    const int* __restrict__ present,  // N_TRIAL x 9
    const float* __restrict__ embed,  // N_STIM x 16
    const float* __restrict__ attw,   // N_GROUP x 16
    float* __restrict__ out)          // N_TRIAL
{
    __shared__ int4  s_stim4[WPB][144];            // 64 trials x 9 ints, dense
    __shared__ float s_d2[WPB][N_REF][D2_STRIDE];  // [ref][trial] transpose

    const int tid  = threadIdx.x;
    const int wv   = tid >> 6;
    const int lane = tid & 63;
    const int q    = lane >> 2;   // quad id 0..15
    const int s    = lane & 3;    // float4 segment 0..3

    int wtb = blockIdx.x * 256 + wv * 64;          // this wave's 64 trials
    const bool valid = (wtb + lane) < N_TRIAL;
    if (wtb > N_TRIAL - 64) wtb = N_TRIAL - 64;    // N_TRIAL % 64 == 0

    // ---- dense coalesced staging of stim (16B-aligned: 64*9*4 = 2304) ----
    {
        const int4* g4 = (const int4*)(stim + wtb * 9);   // 144 int4 per wave
        s_stim4[wv][lane]      = g4[lane];
        s_stim4[wv][64 + lane] = g4[64 + lane];
        if (lane < 16) s_stim4[wv][128 + lane] = g4[128 + lane];
    }

    // ---- group ids for this lane's 4 quad-trials: 4 VGPRs, issued early.
    //      (replaces round-1's wq[4] row preload, which cost 16 VGPRs and
    //       spilled under the launch-bounds pin)
    int gj[4];
#pragma unroll
    for (int j = 0; j < 4; ++j) gj[j] = group[wtb + 16 * j + q];

    // ---- coalesced stream loads, issued early to fly under phase 1 ----
    const int t2 = wtb + lane;                     // phase-2 trial (always valid addr)
    const int* pp = present + t2 * 9;
    v4iu p0 = *(const v4iu*)(pp + 1);              // present[1..4]
    v4iu p1 = *(const v4iu*)(pp + 5);              // present[5..8]
    int  c  = config[t2];

    const float* embed_s = embed + s * 4;          // this lane's row segment

    // ---------------- Phase 1: quad layout, 4 passes x 16 trials ----------
#pragma unroll
    for (int j = 0; j < 4; ++j) {
        const int* sp = (const int*)&s_stim4[wv][0] + (16 * j + q) * 9;
        int idx[9];
#pragma unroll
        for (int i = 0; i < 9; ++i) idx[i] = sp[i];   // conflict-free banks

        // attw: 256B table, L1-hot; latency hidden by ~56 waves/CU
        v4f w  = *(const v4f*)(attw + gj[j] * N_DIM + s * 4);
        v4f zq = *(const v4f*)(embed_s + idx[0] * N_DIM);

        float d2v[N_REF];
#pragma unroll
        for (int r = 0; r < N_REF; ++r) {
            v4f zr = *(const v4f*)(embed_s + idx[1 + r] * N_DIM);
            v4f dd = zq - zr;
            v4f wd = w * dd;
            float d2 = (wd.x * dd.x + wd.y * dd.y) + (wd.z * dd.z + wd.w * dd.w);
            d2v[r] = quad_sum(d2);    // DPP butterfly: full 16-dim sum, VALU pipe
        }
        // lane s persists rows 2s, 2s+1 (uses the quad replication)
        float da = (s == 0) ? d2v[0] : (s == 1) ? d2v[2] : (s == 2) ? d2v[4] : d2v[6];
        float db = (s == 0) ? d2v[1] : (s == 1) ? d2v[3] : (s == 2) ? d2v[5] : d2v[7];
        s_d2[wv][2 * s    ][16 * j + q] = da;
        s_d2[wv][2 * s + 1][16 * j + q] = db;
    }
    // intra-wave ds_write -> ds_read ordering handled by compiler lgkmcnt;
    // no __syncthreads (all LDS state is per-wave).

    // ---------------- Phase 2: thread-per-trial tail -----------------------
    int pr[N_REF] = {p0.x, p0.y, p0.z, p0.w, p1.x, p1.y, p1.z, p1.w};

    float sim[N_REF];
#pragma unroll
    for (int r = 0; r < N_REF; ++r) {
        float d2 = s_d2[wv][r][lane];
        sim[r] = (__expf(-BETA * sqrtf(d2)) + GAMMA) * (float)pr[r];
    }

    int ns = (N_SELECT_PACKED >> ((c & 3) * 4)) & 0xF;   // ns in {1,2,3}

    // only suffix[0..2] can be selected (max N_SELECT == 3)
    float suf2 = sim[7];
#pragma unroll
    for (int r = 6; r >= 2; --r) suf2 += sim[r];
    float suf1 = suf2 + sim[1];
    float suf0 = suf1 + sim[0];

    float num = sim[0] * ((ns >= 2) ? sim[1] : 1.0f) * ((ns >= 3) ? sim[2] : 1.0f);
    float den = suf0   * ((ns >= 2) ? suf1   : 1.0f) * ((ns >= 3) ? suf2   : 1.0f);

    if (valid)
        out[wtb + lane] = __fdividef(num, den);   // fully coalesced store
}

extern "C" void kernel_launch(void* const* d_in, const int* in_sizes, int n_in,
                              void* d_out, int out_size, void* d_ws, size_t ws_size,
                              hipStream_t stream) {
    const int*   stim    = (const int*)d_in[0];
    const int*   config  = (const int*)d_in[1];
    const int*   group   = (const int*)d_in[2];
    const int*   present = (const int*)d_in[3];
    const float* embed   = (const float*)d_in[4];
    const float* attw    = (const float*)d_in[5];
    float*       out     = (float*)d_out;

    int blocks = (N_TRIAL + 255) / 256;   // 3907; tail handled by clamp+valid
    likelihood_kernel<<<blocks, 256, 0, stream>>>(stim, config, group, present,
                                                  embed, attw, out);
}